// Round 1
// baseline (1503.529 us; speedup 1.0000x reference)
//
#include <hip/hip_runtime.h>
#include <math.h>

#define E_NUM 800000
#define CH 256

// ----------------------------- CSR build ------------------------------------

__global__ __launch_bounds__(256) void k_deg(const int* __restrict__ dst, int n,
                                             int* __restrict__ deg) {
  int e = blockIdx.x * 256 + threadIdx.x;
  if (e < E_NUM) { int d = dst[e]; if (d < n) atomicAdd(&deg[d], 1); }
}

__global__ __launch_bounds__(256) void k_scan_block(const int* __restrict__ deg, int n,
                                                    int* __restrict__ incl,
                                                    int* __restrict__ bsum) {
  __shared__ int s[256];
  int i = blockIdx.x * 256 + threadIdx.x;
  int v = (i < n) ? deg[i] : 0;
  s[threadIdx.x] = v;
  __syncthreads();
  for (int o = 1; o < 256; o <<= 1) {
    int t = (threadIdx.x >= o) ? s[threadIdx.x - o] : 0;
    __syncthreads();
    s[threadIdx.x] += t;
    __syncthreads();
  }
  if (i < n) incl[i] = s[threadIdx.x];
  if (threadIdx.x == 255) bsum[blockIdx.x] = s[255];
}

__global__ void k_scan_bsum(int* bsum, int nb, int* total_out) {
  if (threadIdx.x == 0 && blockIdx.x == 0) {
    int acc = 0;
    for (int b = 0; b < nb; b++) { int v = bsum[b]; bsum[b] = acc; acc += v; }
    total_out[0] = acc;
  }
}

__global__ __launch_bounds__(256) void k_scan_final(const int* __restrict__ deg,
                                                    const int* __restrict__ incl,
                                                    const int* __restrict__ bsum, int n,
                                                    int* __restrict__ row) {
  int i = blockIdx.x * 256 + threadIdx.x;
  if (i < n) row[i] = incl[i] - deg[i] + bsum[blockIdx.x];
}

__global__ __launch_bounds__(256) void k_copy_int(const int* __restrict__ a,
                                                  int* __restrict__ b, int n) {
  int i = blockIdx.x * 256 + threadIdx.x;
  if (i < n) b[i] = a[i];
}

__global__ __launch_bounds__(256) void k_fill(const int* __restrict__ src,
                                              const int* __restrict__ dst, int n,
                                              int* __restrict__ cursor,
                                              int* __restrict__ col) {
  int e = blockIdx.x * 256 + threadIdx.x;
  if (e < E_NUM) {
    int d = dst[e];
    if (d < n) { int p = atomicAdd(&cursor[d], 1); col[p] = src[e]; }
  }
}

// ----------------------------- max aggregation -------------------------------

template <int C>
__global__ __launch_bounds__(256) void k_aggmax(const float* __restrict__ x,
                                                const int* __restrict__ row,
                                                const int* __restrict__ col,
                                                float* __restrict__ out, int n) {
  const int NPB = 256 / C;
  int node = blockIdx.x * NPB + threadIdx.x / C;
  int c = threadIdx.x % C;
  if (node >= n) return;
  int e0 = row[node], e1 = row[node + 1];
  float m = -INFINITY;
  for (int e = e0; e < e1; e++) {
    int s = col[e];
    m = fmaxf(m, x[(size_t)s * C + c]);
  }
  out[(size_t)node * C + c] = (e1 > e0) ? m : 0.0f;  // empty segment -> 0 (PyG)
}

// ----------------------------- dual GEMM -------------------------------------
// out[M x 256] = opt_relu( A1[MxK] @ W1[Kx256] + A2[MxK] @ W2[Kx256] + bias )

#define BM 128
#define BN 64
#define BK 16

__global__ __launch_bounds__(256) void k_gemm_dual(const float* __restrict__ A1,
                                                   const float* __restrict__ A2,
                                                   const float* __restrict__ W1,
                                                   const float* __restrict__ W2,
                                                   const float* __restrict__ bias,
                                                   float* __restrict__ out, int M, int K,
                                                   int relu) {
  __shared__ float As[BK][BM];
  __shared__ float Bs[BK][BN];
  int bm0 = blockIdx.x * BM;
  int bn0 = blockIdx.y * BN;
  int t = threadIdx.x;
  int tx = t % 16, ty = t / 16;
  float acc[8][4] = {};
  int K2 = 2 * K;
  for (int kb = 0; kb < K2; kb += BK) {
    const float* A = (kb < K) ? A1 : A2;
    const float* W = (kb < K) ? W1 : W2;
    int k0 = (kb < K) ? kb : (kb - K);
    {
      int r = t / 4;            // 0..63
      int kc = (t % 4) * 4;     // 0,4,8,12
#pragma unroll
      for (int h = 0; h < 2; h++) {
        int row = bm0 + h * 64 + r;
        float4 v = make_float4(0.f, 0.f, 0.f, 0.f);
        if (row < M) v = *(const float4*)&A[(size_t)row * K + k0 + kc];
        As[kc + 0][h * 64 + r] = v.x;
        As[kc + 1][h * 64 + r] = v.y;
        As[kc + 2][h * 64 + r] = v.z;
        As[kc + 3][h * 64 + r] = v.w;
      }
      int kr = t / 16;          // 0..15
      int nc = (t % 16) * 4;    // 0..60
      *(float4*)&Bs[kr][nc] = *(const float4*)&W[(size_t)(k0 + kr) * CH + bn0 + nc];
    }
    __syncthreads();
#pragma unroll
    for (int kk = 0; kk < BK; kk++) {
      float4 a0 = *(const float4*)&As[kk][ty * 8];
      float4 a1 = *(const float4*)&As[kk][ty * 8 + 4];
      float4 b = *(const float4*)&Bs[kk][tx * 4];
      float a[8] = {a0.x, a0.y, a0.z, a0.w, a1.x, a1.y, a1.z, a1.w};
      float bb[4] = {b.x, b.y, b.z, b.w};
#pragma unroll
      for (int i = 0; i < 8; i++)
#pragma unroll
        for (int j = 0; j < 4; j++) acc[i][j] += a[i] * bb[j];
    }
    __syncthreads();
  }
#pragma unroll
  for (int i = 0; i < 8; i++) {
    int row = bm0 + ty * 8 + i;
    if (row >= M) continue;
#pragma unroll
    for (int j = 0; j < 4; j++) {
      int c = bn0 + tx * 4 + j;
      float v = acc[i][j] + bias[c];
      if (relu) v = fmaxf(v, 0.f);
      out[(size_t)row * CH + c] = v;
    }
  }
}

// ----------------------------- pooling ---------------------------------------

__global__ void k_wnorm(const float* __restrict__ w, float* __restrict__ outn) {
  __shared__ float s[256];
  int c = threadIdx.x;
  float v = w[c];
  s[c] = v * v;
  __syncthreads();
  for (int o = 128; o > 0; o >>= 1) {
    if (c < o) s[c] += s[c + o];
    __syncthreads();
  }
  if (c == 0) outn[0] = sqrtf(s[0]);
}

__global__ __launch_bounds__(256) void k_score(const float* __restrict__ x,
                                               const float* __restrict__ w,
                                               const float* __restrict__ wnorm,
                                               unsigned* __restrict__ keys,
                                               float* __restrict__ tanhv) {
  int node = blockIdx.x;
  int c = threadIdx.x;
  float v = x[(size_t)node * CH + c] * w[c];
  __shared__ float s[256];
  s[c] = v;
  __syncthreads();
  for (int o = 128; o > 0; o >>= 1) {
    if (c < o) s[c] += s[c + o];
    __syncthreads();
  }
  if (c == 0) {
    float p = s[0] / wnorm[0];
    float t = tanhf(p);
    unsigned b = __float_as_uint(p);
    unsigned u = (b & 0x80000000u) ? ~b : (b | 0x80000000u);  // order-preserving
    keys[node] = u;
    tanhv[node] = t;
  }
}

// state: [0]=prefix [1]=kneed [2]=cnt_keep [3]=cnt_eq [4]=wnorm(float bits)
__global__ void k_sel_init(unsigned* state, int k) {
  if (threadIdx.x == 0 && blockIdx.x == 0) {
    state[0] = 0u;
    state[1] = (unsigned)k;
  }
}

__global__ __launch_bounds__(256) void k_sel_hist(const unsigned* __restrict__ keys, int n,
                                                  const unsigned* __restrict__ state,
                                                  unsigned* __restrict__ hist, int pass) {
  __shared__ unsigned h[256];
  h[threadIdx.x] = 0;
  __syncthreads();
  unsigned prefix = state[0];
  unsigned mask = (pass == 0) ? 0u : (0xFFFFFFFFu << (32 - 8 * pass));
  int shift = 24 - 8 * pass;
  for (int i = blockIdx.x * 256 + threadIdx.x; i < n; i += gridDim.x * 256) {
    unsigned u = keys[i];
    if (((u ^ prefix) & mask) == 0) atomicAdd(&h[(u >> shift) & 0xFFu], 1u);
  }
  __syncthreads();
  if (h[threadIdx.x]) atomicAdd(&hist[threadIdx.x], h[threadIdx.x]);
}

__global__ void k_sel_resolve(unsigned* state, const unsigned* hist, int pass) {
  if (threadIdx.x == 0 && blockIdx.x == 0) {
    int shift = 24 - 8 * pass;
    unsigned kneed = state[1];
    unsigned cum = 0;
    for (int b = 255; b >= 0; b--) {
      unsigned c = hist[b];
      if (cum + c >= kneed) {
        state[0] |= ((unsigned)b) << shift;
        state[1] = kneed - cum;
        break;
      }
      cum += c;
    }
  }
}

__global__ __launch_bounds__(256) void k_mapinit(int* __restrict__ mapping, int n1) {
  int i = blockIdx.x * 256 + threadIdx.x;
  if (i < n1) mapping[i] = -1;
}

__global__ __launch_bounds__(256) void k_compact(const unsigned* __restrict__ keys, int n,
                                                 unsigned* __restrict__ state,
                                                 int* __restrict__ perm,
                                                 int* __restrict__ mapping) {
  int i = blockIdx.x * 256 + threadIdx.x;
  if (i >= n) return;
  unsigned Kth = state[0];
  unsigned kneed = state[1];
  unsigned u = keys[i];
  int keep = 0;
  if (u > Kth) {
    keep = 1;
  } else if (u == Kth) {
    unsigned t = atomicAdd(&state[3], 1u);
    if (t < kneed) keep = 1;
  }
  if (keep) {
    unsigned p = atomicAdd(&state[2], 1u);
    perm[p] = i;
    mapping[i] = (int)p;
  }
}

__global__ __launch_bounds__(256) void k_gather(const float* __restrict__ x,
                                                const int* __restrict__ perm,
                                                const float* __restrict__ tanhv,
                                                float* __restrict__ out) {
  int node = blockIdx.x;
  int c = threadIdx.x;
  int i = perm[node];
  out[(size_t)node * CH + c] = x[(size_t)i * CH + c] * tanhv[i];
}

__global__ __launch_bounds__(256) void k_relabel(const int* __restrict__ srcIn,
                                                 const int* __restrict__ dstIn,
                                                 const int* __restrict__ mapping, int kNew,
                                                 int* __restrict__ srcOut,
                                                 int* __restrict__ dstOut) {
  int e = blockIdx.x * 256 + threadIdx.x;
  if (e >= E_NUM) return;
  int ns = mapping[srcIn[e]];
  int nd = mapping[dstIn[e]];
  if (ns >= 0 && nd >= 0) {
    srcOut[e] = ns;
    dstOut[e] = nd;
  } else {
    srcOut[e] = 0;
    dstOut[e] = kNew;  // dummy node, dropped by CSR build
  }
}

// ----------------------------- decoder ---------------------------------------

__global__ __launch_bounds__(256) void k_upsum(float* __restrict__ resx,
                                               const float* __restrict__ xc,
                                               const int* __restrict__ mapping) {
  int node = blockIdx.x;
  int c = threadIdx.x;
  int m = mapping[node];
  if (m >= 0) resx[(size_t)node * CH + c] += xc[(size_t)m * CH + c];
}

// last layer: fused maxagg + dual GEMM (K=256 -> 3) + tanh*0.5
__global__ __launch_bounds__(256) void k_final(const float* __restrict__ X,
                                               const int* __restrict__ row,
                                               const int* __restrict__ col,
                                               const float* __restrict__ wl,
                                               const float* __restrict__ wr,
                                               const float* __restrict__ b,
                                               float* __restrict__ out) {
  int node = blockIdx.x;
  int c = threadIdx.x;
  int e0 = row[node], e1 = row[node + 1];
  float m = -INFINITY;
  for (int e = e0; e < e1; e++) m = fmaxf(m, X[(size_t)col[e] * CH + c]);
  float a = (e1 > e0) ? m : 0.f;
  float s = X[(size_t)node * CH + c];
  float p0 = a * wl[c * 3 + 0] + s * wr[c * 3 + 0];
  float p1 = a * wl[c * 3 + 1] + s * wr[c * 3 + 1];
  float p2 = a * wl[c * 3 + 2] + s * wr[c * 3 + 2];
  __shared__ float sh[3][256];
  sh[0][c] = p0;
  sh[1][c] = p1;
  sh[2][c] = p2;
  __syncthreads();
  for (int o = 128; o > 0; o >>= 1) {
    if (c < o) {
      sh[0][c] += sh[0][c + o];
      sh[1][c] += sh[1][c + o];
      sh[2][c] += sh[2][c + o];
    }
    __syncthreads();
  }
  if (c < 3) out[(size_t)node * 3 + c] = tanhf(sh[c][0] + b[c]) * 0.5f;
}

// ----------------------------- host ------------------------------------------

extern "C" void kernel_launch(void* const* d_in, const int* in_sizes, int n_in,
                              void* d_out, int out_size, void* d_ws, size_t ws_size,
                              hipStream_t stream) {
  (void)in_sizes; (void)n_in; (void)out_size; (void)ws_size;
  const float* xin = (const float*)d_in[0];
  const int* ei = (const int*)d_in[1];
  const int* src0 = ei;
  const int* dst0 = ei + E_NUM;
  const float* w0l = (const float*)d_in[2];
  const float* w0r = (const float*)d_in[3];
  const float* b0 = (const float*)d_in[4];
  const float* dwl = (const float*)d_in[5];
  const float* dwr = (const float*)d_in[6];
  const float* db = (const float*)d_in[7];
  const float* poolw = (const float*)d_in[8];
  const float* uwl = (const float*)d_in[9];
  const float* uwr = (const float*)d_in[10];
  const float* ub = (const float*)d_in[11];
  const float* uwlL = (const float*)d_in[12];
  const float* uwrL = (const float*)d_in[13];
  const float* ubL = (const float*)d_in[14];
  float* out = (float*)d_out;

  char* base = (char*)d_ws;
  size_t off = 0;
  auto alloc = [&](size_t bytes) -> void* {
    void* p = base + off;
    off = (off + bytes + 255) & ~(size_t)255;
    return p;
  };

  const int n0 = 50000, n1 = 25000, n2 = 12500, n3 = 6250;
  float* X0 = (float*)alloc((size_t)n0 * CH * 4);
  float* X1 = (float*)alloc((size_t)n1 * CH * 4);
  float* X2 = (float*)alloc((size_t)n2 * CH * 4);
  float* X3 = (float*)alloc((size_t)n3 * CH * 4);
  float* AGG = (float*)alloc((size_t)n1 * CH * 4);  // max concurrent agg
  float* PD = (float*)alloc((size_t)n1 * CH * 4);   // pooled feats / decoder out
  int* eA = (int*)alloc((size_t)2 * E_NUM * 4);
  int* eB = (int*)alloc((size_t)2 * E_NUM * 4);
  int* col0 = (int*)alloc((size_t)E_NUM * 4);
  int* col1 = (int*)alloc((size_t)E_NUM * 4);
  int* col2 = (int*)alloc((size_t)E_NUM * 4);
  int* col3 = (int*)alloc((size_t)E_NUM * 4);
  int* row0 = (int*)alloc((size_t)(n0 + 1) * 4);
  int* row1 = (int*)alloc((size_t)(n1 + 1) * 4);
  int* row2 = (int*)alloc((size_t)(n2 + 1) * 4);
  int* row3 = (int*)alloc((size_t)(n3 + 1) * 4);
  int* map1 = (int*)alloc((size_t)(n0 + 1) * 4);
  int* map2 = (int*)alloc((size_t)(n1 + 1) * 4);
  int* map3 = (int*)alloc((size_t)(n2 + 1) * 4);
  int* perm = (int*)alloc((size_t)n1 * 4);
  unsigned* keys = (unsigned*)alloc((size_t)n0 * 4);
  float* tanhv = (float*)alloc((size_t)n0 * 4);
  int* deg = (int*)alloc((size_t)n0 * 4);
  int* incl = (int*)alloc((size_t)n0 * 4);
  int* cursor = (int*)alloc((size_t)n0 * 4);
  int* bsum = (int*)alloc((size_t)256 * 4);
  unsigned* state = (unsigned*)alloc(1024);
  unsigned* hist = (unsigned*)alloc(1024);

  const int EG = (E_NUM + 255) / 256;

  auto buildCSR = [&](const int* esrc, const int* edst, int n, int* rowp, int* colp) {
    hipMemsetAsync(deg, 0, (size_t)n * 4, stream);
    k_deg<<<EG, 256, 0, stream>>>(edst, n, deg);
    int nb = (n + 255) / 256;
    k_scan_block<<<nb, 256, 0, stream>>>(deg, n, incl, bsum);
    k_scan_bsum<<<1, 1, 0, stream>>>(bsum, nb, rowp + n);
    k_scan_final<<<nb, 256, 0, stream>>>(deg, incl, bsum, n, rowp);
    k_copy_int<<<nb, 256, 0, stream>>>(rowp, cursor, n);
    k_fill<<<EG, 256, 0, stream>>>(esrc, edst, n, cursor, colp);
  };

  auto poolLevel = [&](const float* X, const float* pw, int n, int k, int* mapping,
                       const int* esrcIn, const int* edstIn, int* esrcOut, int* edstOut,
                       float* Pout) {
    k_wnorm<<<1, 256, 0, stream>>>(pw, (float*)(state + 4));
    k_score<<<n, 256, 0, stream>>>(X, pw, (const float*)(state + 4), keys, tanhv);
    k_sel_init<<<1, 1, 0, stream>>>(state, k);
    for (int p = 0; p < 4; p++) {
      hipMemsetAsync(hist, 0, 1024, stream);
      k_sel_hist<<<256, 256, 0, stream>>>(keys, n, state, hist, p);
      k_sel_resolve<<<1, 1, 0, stream>>>(state, hist, p);
    }
    hipMemsetAsync(state + 2, 0, 8, stream);
    k_mapinit<<<(n + 1 + 255) / 256, 256, 0, stream>>>(mapping, n + 1);
    k_compact<<<(n + 255) / 256, 256, 0, stream>>>(keys, n, state, perm, mapping);
    k_gather<<<k, 256, 0, stream>>>(X, perm, tanhv, Pout);
    k_relabel<<<EG, 256, 0, stream>>>(esrcIn, edstIn, mapping, k, esrcOut, edstOut);
  };

  // ---------------- encoder ----------------
  buildCSR(src0, dst0, n0, row0, col0);
  k_aggmax<32><<<(n0 + 7) / 8, 256, 0, stream>>>(xin, row0, col0, AGG, n0);
  k_gemm_dual<<<dim3((n0 + BM - 1) / BM, CH / BN), 256, 0, stream>>>(AGG, xin, w0l, w0r, b0,
                                                                     X0, n0, 32, 1);

  // pool 1 (50000 -> 25000)
  poolLevel(X0, poolw + 0 * CH, n0, n1, map1, src0, dst0, eA, eA + E_NUM, PD);
  buildCSR(eA, eA + E_NUM, n1, row1, col1);
  k_aggmax<256><<<n1, 256, 0, stream>>>(PD, row1, col1, AGG, n1);
  k_gemm_dual<<<dim3((n1 + BM - 1) / BM, CH / BN), 256, 0, stream>>>(
      AGG, PD, dwl + 0 * CH * CH, dwr + 0 * CH * CH, db + 0 * CH, X1, n1, CH, 1);

  // pool 2 (25000 -> 12500)
  poolLevel(X1, poolw + 1 * CH, n1, n2, map2, eA, eA + E_NUM, eB, eB + E_NUM, PD);
  buildCSR(eB, eB + E_NUM, n2, row2, col2);
  k_aggmax<256><<<n2, 256, 0, stream>>>(PD, row2, col2, AGG, n2);
  k_gemm_dual<<<dim3((n2 + BM - 1) / BM, CH / BN), 256, 0, stream>>>(
      AGG, PD, dwl + 1 * CH * CH, dwr + 1 * CH * CH, db + 1 * CH, X2, n2, CH, 1);

  // pool 3 (12500 -> 6250)
  poolLevel(X2, poolw + 2 * CH, n2, n3, map3, eB, eB + E_NUM, eA, eA + E_NUM, PD);
  buildCSR(eA, eA + E_NUM, n3, row3, col3);
  k_aggmax<256><<<n3, 256, 0, stream>>>(PD, row3, col3, AGG, n3);
  k_gemm_dual<<<dim3((n3 + BM - 1) / BM, CH / BN), 256, 0, stream>>>(
      AGG, PD, dwl + 2 * CH * CH, dwr + 2 * CH * CH, db + 2 * CH, X3, n3, CH, 1);

  // ---------------- decoder ----------------
  // level 2
  k_upsum<<<n2, 256, 0, stream>>>(X2, X3, map3);
  k_aggmax<256><<<n2, 256, 0, stream>>>(X2, row2, col2, AGG, n2);
  k_gemm_dual<<<dim3((n2 + BM - 1) / BM, CH / BN), 256, 0, stream>>>(
      AGG, X2, uwl + 0 * CH * CH, uwr + 0 * CH * CH, ub + 0 * CH, PD, n2, CH, 1);

  // level 1
  k_upsum<<<n1, 256, 0, stream>>>(X1, PD, map2);
  k_aggmax<256><<<n1, 256, 0, stream>>>(X1, row1, col1, AGG, n1);
  k_gemm_dual<<<dim3((n1 + BM - 1) / BM, CH / BN), 256, 0, stream>>>(
      AGG, X1, uwl + 1 * CH * CH, uwr + 1 * CH * CH, ub + 1 * CH, PD, n1, CH, 1);

  // level 0 (fused agg + 256->3 GEMM + tanh*0.5)
  k_upsum<<<n0, 256, 0, stream>>>(X0, PD, map1);
  k_final<<<n0, 256, 0, stream>>>(X0, row0, col0, uwlL, uwrL, ubL, out);
}

// Round 2
// 1295.468 us; speedup vs baseline: 1.1606x; 1.1606x over previous
//
#include <hip/hip_runtime.h>
#include <math.h>

#define E_NUM 800000
#define CH 256

// ----------------------------- CSR build ------------------------------------

__global__ __launch_bounds__(256) void k_deg(const int* __restrict__ dst, int n,
                                             int* __restrict__ deg) {
  int e = blockIdx.x * 256 + threadIdx.x;
  if (e < E_NUM) { int d = dst[e]; if (d < n) atomicAdd(&deg[d], 1); }
}

__global__ __launch_bounds__(256) void k_scan_block(const int* __restrict__ deg, int n,
                                                    int* __restrict__ incl,
                                                    int* __restrict__ bsum) {
  __shared__ int s[256];
  int i = blockIdx.x * 256 + threadIdx.x;
  int v = (i < n) ? deg[i] : 0;
  s[threadIdx.x] = v;
  __syncthreads();
  for (int o = 1; o < 256; o <<= 1) {
    int t = (threadIdx.x >= o) ? s[threadIdx.x - o] : 0;
    __syncthreads();
    s[threadIdx.x] += t;
    __syncthreads();
  }
  if (i < n) incl[i] = s[threadIdx.x];
  if (threadIdx.x == 255) bsum[blockIdx.x] = s[255];
}

__global__ void k_scan_bsum(int* bsum, int nb, int* total_out) {
  if (threadIdx.x == 0 && blockIdx.x == 0) {
    int acc = 0;
    for (int b = 0; b < nb; b++) { int v = bsum[b]; bsum[b] = acc; acc += v; }
    total_out[0] = acc;
  }
}

// writes both row[] and cursor[] (cursor copy folded in)
__global__ __launch_bounds__(256) void k_scan_final(const int* __restrict__ deg,
                                                    const int* __restrict__ incl,
                                                    const int* __restrict__ bsum, int n,
                                                    int* __restrict__ row,
                                                    int* __restrict__ cursor) {
  int i = blockIdx.x * 256 + threadIdx.x;
  if (i < n) {
    int r = incl[i] - deg[i] + bsum[blockIdx.x];
    row[i] = r;
    cursor[i] = r;
  }
}

__global__ __launch_bounds__(256) void k_fill(const int* __restrict__ src,
                                              const int* __restrict__ dst, int n,
                                              int* __restrict__ cursor,
                                              int* __restrict__ col) {
  int e = blockIdx.x * 256 + threadIdx.x;
  if (e < E_NUM) {
    int d = dst[e];
    if (d < n) { int p = atomicAdd(&cursor[d], 1); col[p] = src[e]; }
  }
}

// relabel edges AND accumulate degree histogram of the new graph (deg fused)
__global__ __launch_bounds__(256) void k_relabel_deg(const int* __restrict__ srcIn,
                                                     const int* __restrict__ dstIn,
                                                     const int* __restrict__ mapping,
                                                     int kNew, int* __restrict__ srcOut,
                                                     int* __restrict__ dstOut,
                                                     int* __restrict__ deg) {
  int e = blockIdx.x * 256 + threadIdx.x;
  if (e >= E_NUM) return;
  int ns = mapping[srcIn[e]];
  int nd = mapping[dstIn[e]];
  if (ns >= 0 && nd >= 0) {
    srcOut[e] = ns;
    dstOut[e] = nd;
    atomicAdd(&deg[nd], 1);
  } else {
    srcOut[e] = 0;
    dstOut[e] = kNew;  // dummy node, dropped by CSR build
  }
}

// ----------------------------- max aggregation -------------------------------

// C=32 encoder input (each lane one channel, 8 nodes/block)
__global__ __launch_bounds__(256) void k_aggmax32(const float* __restrict__ x,
                                                  const int* __restrict__ row,
                                                  const int* __restrict__ col,
                                                  float* __restrict__ out, int n) {
  int node = blockIdx.x * 8 + threadIdx.x / 32;
  int c = threadIdx.x % 32;
  if (node >= n) return;
  int e0 = row[node], e1 = row[node + 1];
  float m = -INFINITY;
  for (int e = e0; e < e1; e++) m = fmaxf(m, x[(size_t)col[e] * 32 + c]);
  out[(size_t)node * 32 + c] = (e1 > e0) ? m : 0.0f;
}

// C=256: wave-per-node, float4 per lane (full 1KB row per instruction)
__global__ __launch_bounds__(256) void k_aggmax4(const float* __restrict__ x,
                                                 const int* __restrict__ row,
                                                 const int* __restrict__ col,
                                                 float* __restrict__ out, int n) {
  int lane = threadIdx.x & 63;
  int node = blockIdx.x * 4 + (threadIdx.x >> 6);
  if (node >= n) return;
  int e0 = row[node], e1 = row[node + 1];
  float4 m = make_float4(-INFINITY, -INFINITY, -INFINITY, -INFINITY);
  for (int e = e0; e < e1; e++) {
    int s = col[e];
    float4 v = *(const float4*)&x[(size_t)s * CH + lane * 4];
    m.x = fmaxf(m.x, v.x);
    m.y = fmaxf(m.y, v.y);
    m.z = fmaxf(m.z, v.z);
    m.w = fmaxf(m.w, v.w);
  }
  if (e1 <= e0) m = make_float4(0.f, 0.f, 0.f, 0.f);
  *(float4*)&out[(size_t)node * CH + lane * 4] = m;
}

// ----------------------------- dual GEMM -------------------------------------
// out[M x 256] = opt_relu( A1[MxK] @ W1[Kx256] + A2[MxK] @ W2[Kx256] + bias )

#define BM 128
#define BN 64
#define BK 16

__global__ __launch_bounds__(256) void k_gemm_dual(const float* __restrict__ A1,
                                                   const float* __restrict__ A2,
                                                   const float* __restrict__ W1,
                                                   const float* __restrict__ W2,
                                                   const float* __restrict__ bias,
                                                   float* __restrict__ out, int M, int K,
                                                   int relu) {
  __shared__ float As[BK][BM];
  __shared__ float Bs[BK][BN];
  int bm0 = blockIdx.x * BM;
  int bn0 = blockIdx.y * BN;
  int t = threadIdx.x;
  int tx = t % 16, ty = t / 16;
  float acc[8][4] = {};
  int K2 = 2 * K;
  for (int kb = 0; kb < K2; kb += BK) {
    const float* A = (kb < K) ? A1 : A2;
    const float* W = (kb < K) ? W1 : W2;
    int k0 = (kb < K) ? kb : (kb - K);
    {
      int r = t / 4;            // 0..63
      int kc = (t % 4) * 4;     // 0,4,8,12
#pragma unroll
      for (int h = 0; h < 2; h++) {
        int row = bm0 + h * 64 + r;
        float4 v = make_float4(0.f, 0.f, 0.f, 0.f);
        if (row < M) v = *(const float4*)&A[(size_t)row * K + k0 + kc];
        As[kc + 0][h * 64 + r] = v.x;
        As[kc + 1][h * 64 + r] = v.y;
        As[kc + 2][h * 64 + r] = v.z;
        As[kc + 3][h * 64 + r] = v.w;
      }
      int kr = t / 16;          // 0..15
      int nc = (t % 16) * 4;    // 0..60
      *(float4*)&Bs[kr][nc] = *(const float4*)&W[(size_t)(k0 + kr) * CH + bn0 + nc];
    }
    __syncthreads();
#pragma unroll
    for (int kk = 0; kk < BK; kk++) {
      float4 a0 = *(const float4*)&As[kk][ty * 8];
      float4 a1 = *(const float4*)&As[kk][ty * 8 + 4];
      float4 b = *(const float4*)&Bs[kk][tx * 4];
      float a[8] = {a0.x, a0.y, a0.z, a0.w, a1.x, a1.y, a1.z, a1.w};
      float bb[4] = {b.x, b.y, b.z, b.w};
#pragma unroll
      for (int i = 0; i < 8; i++)
#pragma unroll
        for (int j = 0; j < 4; j++) acc[i][j] += a[i] * bb[j];
    }
    __syncthreads();
  }
#pragma unroll
  for (int i = 0; i < 8; i++) {
    int row = bm0 + ty * 8 + i;
    if (row >= M) continue;
#pragma unroll
    for (int j = 0; j < 4; j++) {
      int c = bn0 + tx * 4 + j;
      float v = acc[i][j] + bias[c];
      if (relu) v = fmaxf(v, 0.f);
      out[(size_t)row * CH + c] = v;
    }
  }
}

// ----------------------------- pooling ---------------------------------------

// wave-per-node score; wnorm computed in-wave (no separate kernel)
__global__ __launch_bounds__(256) void k_score(const float* __restrict__ x,
                                               const float* __restrict__ w, int n,
                                               unsigned* __restrict__ keys,
                                               float* __restrict__ tanhv) {
  int lane = threadIdx.x & 63;
  int node = blockIdx.x * 4 + (threadIdx.x >> 6);
  float4 w4 = *(const float4*)&w[lane * 4];
  float nn = w4.x * w4.x + w4.y * w4.y + w4.z * w4.z + w4.w * w4.w;
#pragma unroll
  for (int o = 32; o > 0; o >>= 1) nn += __shfl_down(nn, o);
  nn = __shfl(nn, 0);
  if (node >= n) return;
  float4 x4 = *(const float4*)&x[(size_t)node * CH + lane * 4];
  float s = x4.x * w4.x + x4.y * w4.y + x4.z * w4.z + x4.w * w4.w;
#pragma unroll
  for (int o = 32; o > 0; o >>= 1) s += __shfl_down(s, o);
  if (lane == 0) {
    float p = s / sqrtf(nn);
    unsigned b = __float_as_uint(p);
    unsigned u = (b & 0x80000000u) ? ~b : (b | 0x80000000u);  // order-preserving
    keys[node] = u;
    tanhv[node] = tanhf(p);
  }
}

// single-workgroup 4-pass radix select; writes state = {Kth, kneed, 0, 0}
__global__ __launch_bounds__(1024) void k_select(const unsigned* __restrict__ keys, int n,
                                                 int k, unsigned* __restrict__ state) {
  __shared__ unsigned hist[256];
  __shared__ unsigned sh_prefix, sh_kneed;
  int t = threadIdx.x;
  if (t == 0) { sh_prefix = 0u; sh_kneed = (unsigned)k; }
  __syncthreads();
  for (int pass = 0; pass < 4; pass++) {
    if (t < 256) hist[t] = 0u;
    __syncthreads();
    unsigned prefix = sh_prefix;
    unsigned mask = (pass == 0) ? 0u : (0xFFFFFFFFu << (32 - 8 * pass));
    int shift = 24 - 8 * pass;
    for (int i = t; i < n; i += 1024) {
      unsigned u = keys[i];
      if (((u ^ prefix) & mask) == 0) atomicAdd(&hist[(u >> shift) & 0xFFu], 1u);
    }
    __syncthreads();
    if (t == 0) {
      unsigned kneed = sh_kneed, cum = 0;
      for (int b = 255; b >= 0; b--) {
        unsigned c = hist[b];
        if (cum + c >= kneed) {
          sh_prefix = prefix | (((unsigned)b) << shift);
          sh_kneed = kneed - cum;
          break;
        }
        cum += c;
      }
    }
    __syncthreads();
  }
  if (t == 0) {
    state[0] = sh_prefix;
    state[1] = sh_kneed;
    state[2] = 0u;
    state[3] = 0u;
  }
}

// compaction with mapping init folded in (covers index n for the dummy node)
__global__ __launch_bounds__(256) void k_compact(const unsigned* __restrict__ keys, int n,
                                                 unsigned* __restrict__ state,
                                                 int* __restrict__ perm,
                                                 int* __restrict__ mapping) {
  int i = blockIdx.x * 256 + threadIdx.x;
  if (i > n) return;
  if (i == n) { mapping[n] = -1; return; }
  unsigned Kth = state[0];
  unsigned kneed = state[1];
  unsigned u = keys[i];
  int m = -1;
  if (u > Kth) {
    unsigned p = atomicAdd(&state[2], 1u);
    perm[p] = i;
    m = (int)p;
  } else if (u == Kth) {
    unsigned t = atomicAdd(&state[3], 1u);
    if (t < kneed) {
      unsigned p = atomicAdd(&state[2], 1u);
      perm[p] = i;
      m = (int)p;
    }
  }
  mapping[i] = m;
}

__global__ __launch_bounds__(256) void k_gather(const float* __restrict__ x,
                                                const int* __restrict__ perm,
                                                const float* __restrict__ tanhv,
                                                float* __restrict__ out, int k) {
  int lane = threadIdx.x & 63;
  int node = blockIdx.x * 4 + (threadIdx.x >> 6);
  if (node >= k) return;
  int i = perm[node];
  float t = tanhv[i];
  float4 v = *(const float4*)&x[(size_t)i * CH + lane * 4];
  v.x *= t; v.y *= t; v.z *= t; v.w *= t;
  *(float4*)&out[(size_t)node * CH + lane * 4] = v;
}

// ----------------------------- decoder ---------------------------------------

__global__ __launch_bounds__(256) void k_upsum(float* __restrict__ resx,
                                               const float* __restrict__ xc,
                                               const int* __restrict__ mapping, int n) {
  int lane = threadIdx.x & 63;
  int node = blockIdx.x * 4 + (threadIdx.x >> 6);
  if (node >= n) return;
  int m = mapping[node];
  if (m < 0) return;
  float4 a = *(const float4*)&resx[(size_t)node * CH + lane * 4];
  float4 b = *(const float4*)&xc[(size_t)m * CH + lane * 4];
  a.x += b.x; a.y += b.y; a.z += b.z; a.w += b.w;
  *(float4*)&resx[(size_t)node * CH + lane * 4] = a;
}

// last layer: fused maxagg + dual GEMM (K=256 -> 3) + tanh*0.5, wave-per-node
__global__ __launch_bounds__(256) void k_final(const float* __restrict__ X,
                                               const int* __restrict__ row,
                                               const int* __restrict__ col,
                                               const float* __restrict__ wl,
                                               const float* __restrict__ wr,
                                               const float* __restrict__ b,
                                               float* __restrict__ out, int n) {
  int lane = threadIdx.x & 63;
  int node = blockIdx.x * 4 + (threadIdx.x >> 6);
  if (node >= n) return;
  int e0 = row[node], e1 = row[node + 1];
  float4 m = make_float4(-INFINITY, -INFINITY, -INFINITY, -INFINITY);
  for (int e = e0; e < e1; e++) {
    int s = col[e];
    float4 v = *(const float4*)&X[(size_t)s * CH + lane * 4];
    m.x = fmaxf(m.x, v.x);
    m.y = fmaxf(m.y, v.y);
    m.z = fmaxf(m.z, v.z);
    m.w = fmaxf(m.w, v.w);
  }
  if (e1 <= e0) m = make_float4(0.f, 0.f, 0.f, 0.f);
  float4 s4 = *(const float4*)&X[(size_t)node * CH + lane * 4];
  // wl/wr are [256][3] row-major; lane covers channels 4l..4l+3 -> 12 floats, 16B-aligned
  float wlv[12], wrv[12];
  *(float4*)&wlv[0] = ((const float4*)(wl + 12 * lane))[0];
  *(float4*)&wlv[4] = ((const float4*)(wl + 12 * lane))[1];
  *(float4*)&wlv[8] = ((const float4*)(wl + 12 * lane))[2];
  *(float4*)&wrv[0] = ((const float4*)(wr + 12 * lane))[0];
  *(float4*)&wrv[4] = ((const float4*)(wr + 12 * lane))[1];
  *(float4*)&wrv[8] = ((const float4*)(wr + 12 * lane))[2];
  float av[4] = {m.x, m.y, m.z, m.w};
  float sv[4] = {s4.x, s4.y, s4.z, s4.w};
  float p[3] = {0.f, 0.f, 0.f};
#pragma unroll
  for (int q = 0; q < 4; q++)
#pragma unroll
    for (int j = 0; j < 3; j++) p[j] += av[q] * wlv[q * 3 + j] + sv[q] * wrv[q * 3 + j];
#pragma unroll
  for (int j = 0; j < 3; j++) {
#pragma unroll
    for (int o = 32; o > 0; o >>= 1) p[j] += __shfl_down(p[j], o);
  }
  if (lane == 0) {
#pragma unroll
    for (int j = 0; j < 3; j++) out[(size_t)node * 3 + j] = tanhf(p[j] + b[j]) * 0.5f;
  }
}

// ----------------------------- host ------------------------------------------

extern "C" void kernel_launch(void* const* d_in, const int* in_sizes, int n_in,
                              void* d_out, int out_size, void* d_ws, size_t ws_size,
                              hipStream_t stream) {
  (void)in_sizes; (void)n_in; (void)out_size; (void)ws_size;
  const float* xin = (const float*)d_in[0];
  const int* ei = (const int*)d_in[1];
  const int* src0 = ei;
  const int* dst0 = ei + E_NUM;
  const float* w0l = (const float*)d_in[2];
  const float* w0r = (const float*)d_in[3];
  const float* b0 = (const float*)d_in[4];
  const float* dwl = (const float*)d_in[5];
  const float* dwr = (const float*)d_in[6];
  const float* db = (const float*)d_in[7];
  const float* poolw = (const float*)d_in[8];
  const float* uwl = (const float*)d_in[9];
  const float* uwr = (const float*)d_in[10];
  const float* ub = (const float*)d_in[11];
  const float* uwlL = (const float*)d_in[12];
  const float* uwrL = (const float*)d_in[13];
  const float* ubL = (const float*)d_in[14];
  float* out = (float*)d_out;

  char* base = (char*)d_ws;
  size_t off = 0;
  auto alloc = [&](size_t bytes) -> void* {
    void* p = base + off;
    off = (off + bytes + 255) & ~(size_t)255;
    return p;
  };

  const int n0 = 50000, n1 = 25000, n2 = 12500, n3 = 6250;
  float* X0 = (float*)alloc((size_t)n0 * CH * 4);
  float* X1 = (float*)alloc((size_t)n1 * CH * 4);
  float* X2 = (float*)alloc((size_t)n2 * CH * 4);
  float* X3 = (float*)alloc((size_t)n3 * CH * 4);
  float* AGG = (float*)alloc((size_t)n1 * CH * 4);
  float* PD = (float*)alloc((size_t)n1 * CH * 4);
  int* eA = (int*)alloc((size_t)2 * E_NUM * 4);
  int* eB = (int*)alloc((size_t)2 * E_NUM * 4);
  int* col0 = (int*)alloc((size_t)E_NUM * 4);
  int* col1 = (int*)alloc((size_t)E_NUM * 4);
  int* col2 = (int*)alloc((size_t)E_NUM * 4);
  int* col3 = (int*)alloc((size_t)E_NUM * 4);
  int* row0 = (int*)alloc((size_t)(n0 + 1) * 4);
  int* row1 = (int*)alloc((size_t)(n1 + 1) * 4);
  int* row2 = (int*)alloc((size_t)(n2 + 1) * 4);
  int* row3 = (int*)alloc((size_t)(n3 + 1) * 4);
  int* map1 = (int*)alloc((size_t)(n0 + 1) * 4);
  int* map2 = (int*)alloc((size_t)(n1 + 1) * 4);
  int* map3 = (int*)alloc((size_t)(n2 + 1) * 4);
  int* perm = (int*)alloc((size_t)n1 * 4);
  unsigned* keys = (unsigned*)alloc((size_t)n0 * 4);
  float* tanhv = (float*)alloc((size_t)n0 * 4);
  int* deg = (int*)alloc((size_t)n0 * 4);
  int* incl = (int*)alloc((size_t)n0 * 4);
  int* cursor = (int*)alloc((size_t)n0 * 4);
  int* bsum = (int*)alloc((size_t)256 * 4);
  unsigned* state = (unsigned*)alloc(1024);

  const int EG = (E_NUM + 255) / 256;

  // scan + fill part of CSR build (deg[] must already be populated)
  auto csrRest = [&](const int* esrc, const int* edst, int n, int* rowp, int* colp) {
    int nb = (n + 255) / 256;
    k_scan_block<<<nb, 256, 0, stream>>>(deg, n, incl, bsum);
    k_scan_bsum<<<1, 1, 0, stream>>>(bsum, nb, rowp + n);
    k_scan_final<<<nb, 256, 0, stream>>>(deg, incl, bsum, n, rowp, cursor);
    k_fill<<<EG, 256, 0, stream>>>(esrc, edst, n, cursor, colp);
  };

  auto poolLevel = [&](const float* X, const float* pw, int n, int k, int* mapping,
                       const int* esrcIn, const int* edstIn, int* esrcOut, int* edstOut,
                       float* Pout) {
    k_score<<<(n + 3) / 4, 256, 0, stream>>>(X, pw, n, keys, tanhv);
    k_select<<<1, 1024, 0, stream>>>(keys, n, k, state);
    k_compact<<<(n + 1 + 255) / 256, 256, 0, stream>>>(keys, n, state, perm, mapping);
    k_gather<<<(k + 3) / 4, 256, 0, stream>>>(X, perm, tanhv, Pout, k);
    hipMemsetAsync(deg, 0, (size_t)k * 4, stream);
    k_relabel_deg<<<EG, 256, 0, stream>>>(esrcIn, edstIn, mapping, k, esrcOut, edstOut, deg);
  };

  // ---------------- encoder ----------------
  hipMemsetAsync(deg, 0, (size_t)n0 * 4, stream);
  k_deg<<<EG, 256, 0, stream>>>(dst0, n0, deg);
  csrRest(src0, dst0, n0, row0, col0);
  k_aggmax32<<<(n0 + 7) / 8, 256, 0, stream>>>(xin, row0, col0, AGG, n0);
  k_gemm_dual<<<dim3((n0 + BM - 1) / BM, CH / BN), 256, 0, stream>>>(AGG, xin, w0l, w0r, b0,
                                                                     X0, n0, 32, 1);

  // pool 1 (50000 -> 25000)
  poolLevel(X0, poolw + 0 * CH, n0, n1, map1, src0, dst0, eA, eA + E_NUM, PD);
  csrRest(eA, eA + E_NUM, n1, row1, col1);
  k_aggmax4<<<(n1 + 3) / 4, 256, 0, stream>>>(PD, row1, col1, AGG, n1);
  k_gemm_dual<<<dim3((n1 + BM - 1) / BM, CH / BN), 256, 0, stream>>>(
      AGG, PD, dwl + 0 * CH * CH, dwr + 0 * CH * CH, db + 0 * CH, X1, n1, CH, 1);

  // pool 2 (25000 -> 12500)
  poolLevel(X1, poolw + 1 * CH, n1, n2, map2, eA, eA + E_NUM, eB, eB + E_NUM, PD);
  csrRest(eB, eB + E_NUM, n2, row2, col2);
  k_aggmax4<<<(n2 + 3) / 4, 256, 0, stream>>>(PD, row2, col2, AGG, n2);
  k_gemm_dual<<<dim3((n2 + BM - 1) / BM, CH / BN), 256, 0, stream>>>(
      AGG, PD, dwl + 1 * CH * CH, dwr + 1 * CH * CH, db + 1 * CH, X2, n2, CH, 1);

  // pool 3 (12500 -> 6250)
  poolLevel(X2, poolw + 2 * CH, n2, n3, map3, eB, eB + E_NUM, eA, eA + E_NUM, PD);
  csrRest(eA, eA + E_NUM, n3, row3, col3);
  k_aggmax4<<<(n3 + 3) / 4, 256, 0, stream>>>(PD, row3, col3, AGG, n3);
  k_gemm_dual<<<dim3((n3 + BM - 1) / BM, CH / BN), 256, 0, stream>>>(
      AGG, PD, dwl + 2 * CH * CH, dwr + 2 * CH * CH, db + 2 * CH, X3, n3, CH, 1);

  // ---------------- decoder ----------------
  k_upsum<<<(n2 + 3) / 4, 256, 0, stream>>>(X2, X3, map3, n2);
  k_aggmax4<<<(n2 + 3) / 4, 256, 0, stream>>>(X2, row2, col2, AGG, n2);
  k_gemm_dual<<<dim3((n2 + BM - 1) / BM, CH / BN), 256, 0, stream>>>(
      AGG, X2, uwl + 0 * CH * CH, uwr + 0 * CH * CH, ub + 0 * CH, PD, n2, CH, 1);

  k_upsum<<<(n1 + 3) / 4, 256, 0, stream>>>(X1, PD, map2, n1);
  k_aggmax4<<<(n1 + 3) / 4, 256, 0, stream>>>(X1, row1, col1, AGG, n1);
  k_gemm_dual<<<dim3((n1 + BM - 1) / BM, CH / BN), 256, 0, stream>>>(
      AGG, X1, uwl + 1 * CH * CH, uwr + 1 * CH * CH, ub + 1 * CH, PD, n1, CH, 1);

  k_upsum<<<(n0 + 3) / 4, 256, 0, stream>>>(X0, PD, map1, n0);
  k_final<<<(n0 + 3) / 4, 256, 0, stream>>>(X0, row0, col0, uwlL, uwrL, ubL, out, n0);
}